// Round 5
// baseline (581.333 us; speedup 1.0000x reference)
//
#include <hip/hip_runtime.h>
#include <hip/hip_bf16.h>

#define DEV __device__ __forceinline__

namespace {

constexpr int D     = 1024;
constexpr int F     = 2048;
constexpr int E     = 8;
constexpr int TWO_F = 2 * F;

typedef short bf16x8 __attribute__((ext_vector_type(8)));
typedef float f32x4  __attribute__((ext_vector_type(4)));

DEV unsigned short f32_to_bf16(float f) {
  unsigned int u = __builtin_bit_cast(unsigned int, f);
  u += 0x7fffu + ((u >> 16) & 1u);   // RNE
  return (unsigned short)(u >> 16);
}

DEV float bf16_to_f32(unsigned short h) {
  unsigned int u = ((unsigned int)h) << 16;
  return __builtin_bit_cast(float, u);
}

// async global->LDS, 16B per lane; LDS dest is wave-uniform base + lane*16 implicit
DEV void load_lds16(const void* g, void* l) {
  __builtin_amdgcn_global_load_lds((const __attribute__((address_space(1))) void*)g,
                                   (__attribute__((address_space(3))) void*)l, 16, 0, 0);
}

// XOR-swizzled fragment address: LDS[row][c] holds global chunk c ^ (row&7).
DEV const bf16x8* frag_addr(const unsigned short* S, int row, int kk, int quad) {
  int cl = (((kk >> 3) + quad) ^ (row & 7));
  return (const bf16x8*)(S + row * 64 + cl * 8);
}

// One fused fp32->bf16 conversion over x, W1, W2 (sizes are multiples of 2048 elems).
__global__ void cvt_all_kernel(const float* __restrict__ x, const float* __restrict__ W1,
                               const float* __restrict__ W2,
                               unsigned short* __restrict__ xb, unsigned short* __restrict__ W1b,
                               unsigned short* __restrict__ W2b,
                               long long nx, long long n1) {
  long long i = (long long)(blockIdx.x * 256 + threadIdx.x) * 8;
  const float* src;
  unsigned short* dst;
  long long off;
  if (i < nx)            { src = x;  dst = xb;  off = i; }
  else if (i < nx + n1)  { src = W1; dst = W1b; off = i - nx; }
  else                   { src = W2; dst = W2b; off = i - nx - n1; }
  float4 a = *(const float4*)(src + off);
  float4 b = *(const float4*)(src + off + 4);
  uint4 o;
  o.x = (unsigned)f32_to_bf16(a.x) | ((unsigned)f32_to_bf16(a.y) << 16);
  o.y = (unsigned)f32_to_bf16(a.z) | ((unsigned)f32_to_bf16(a.w) << 16);
  o.z = (unsigned)f32_to_bf16(b.x) | ((unsigned)f32_to_bf16(b.y) << 16);
  o.w = (unsigned)f32_to_bf16(b.z) | ((unsigned)f32_to_bf16(b.w) << 16);
  *(uint4*)(dst + off) = o;
}

// Router: one wave per token; fp32 dot over D=1024, top-2 + softmax. NO atomics.
__global__ void router_kernel(const float* __restrict__ x, const float* __restrict__ Wr,
                              const float* __restrict__ temp,
                              int* __restrict__ topk_idx, float* __restrict__ topk_gate, int T) {
  int wid  = blockIdx.x * 4 + (threadIdx.x >> 6);
  int lane = threadIdx.x & 63;
  if (wid >= T) return;
  const float* xr = x + (size_t)wid * D;
  float acc[E];
#pragma unroll
  for (int e = 0; e < E; ++e) acc[e] = 0.f;
  int base = lane * 16;
#pragma unroll
  for (int u = 0; u < 4; ++u) {
    float4 xv = *(const float4*)(xr + base + u * 4);
#pragma unroll
    for (int e = 0; e < E; ++e) {
      float4 wv = *(const float4*)(Wr + e * D + base + u * 4);
      acc[e] += xv.x * wv.x + xv.y * wv.y + xv.z * wv.z + xv.w * wv.w;
    }
  }
#pragma unroll
  for (int e = 0; e < E; ++e) {
    float v = acc[e];
#pragma unroll
    for (int off = 32; off > 0; off >>= 1) v += __shfl_xor(v, off, 64);
    acc[e] = v;
  }
  if (lane == 0) {
    float inv = 1.0f / temp[0];
    float l[E];
#pragma unroll
    for (int e = 0; e < E; ++e) l[e] = acc[e] * inv;
    int e0 = 0;
#pragma unroll
    for (int e = 1; e < E; ++e) if (l[e] > l[e0]) e0 = e;   // first-index tie-break like top_k
    int e1 = (e0 == 0) ? 1 : 0;
#pragma unroll
    for (int e = 0; e < E; ++e) if (e != e0 && l[e] > l[e1]) e1 = e;
    float dlt = l[e1] - l[e0];
    float ed  = __expf(dlt);
    topk_idx[2 * wid]      = e0;
    topk_idx[2 * wid + 1]  = e1;
    topk_gate[2 * wid]     = 1.f / (1.f + ed);
    topk_gate[2 * wid + 1] = ed / (1.f + ed);
  }
}

// Single block, 1024 threads (16 waves x 8 chunks x 64 lanes covers 2T<=8192 slots).
// Ballot-based histogram + rank: zero LDS-atomic serialization.
// Emits compacted per-expert lists AND pos[q] = pair slot of routing slot q (for combine).
__global__ __launch_bounds__(1024)
void assign_kernel(const int* __restrict__ topk_idx, const float* __restrict__ topk_gate,
                   int* __restrict__ counts, int* __restrict__ offsets_g,
                   int* __restrict__ row_token, float* __restrict__ row_gate,
                   int* __restrict__ pos, int T) {
  __shared__ int cntS[128 * E];
  __shared__ int baseS[128 * E];
  __shared__ int totS[E];
  __shared__ int offS[E];
  const int tid  = threadIdx.x;
  const int w    = tid >> 6;
  const int lane = tid & 63;
  const int Q    = 2 * T;
  const unsigned long long lm = (1ull << lane) - 1ull;

  int eReg[8], rReg[8];
#pragma unroll
  for (int c = 0; c < 8; ++c) {
    int q = (w * 8 + c) * 64 + lane;
    int e = (q < Q) ? topk_idx[q] : -1;
    eReg[c] = e;
    int r = 0;
#pragma unroll
    for (int ee = 0; ee < E; ++ee) {
      unsigned long long m = __ballot(e == ee);
      if (lane == ee) cntS[(w * 8 + c) * E + ee] = __popcll(m);
      if (e == ee) r = __popcll(m & lm);
    }
    rReg[c] = r;
  }
  __syncthreads();
  if (tid < E) {             // serial scan over the 128 (wave,chunk) groups, one thread per expert
    int s = 0;
    for (int k = 0; k < 128; ++k) { baseS[k * E + tid] = s; s += cntS[k * E + tid]; }
    totS[tid] = s;
  }
  __syncthreads();
  if (tid == 0) {
    int s = 0;
    for (int e = 0; e < E; ++e) {
      offS[e] = s;
      counts[e] = totS[e];
      offsets_g[e] = s;
      s += totS[e];
    }
  }
  __syncthreads();
#pragma unroll
  for (int c = 0; c < 8; ++c) {
    int q = (w * 8 + c) * 64 + lane;
    if (q < Q) {
      int e = eReg[c];
      int p = offS[e] + baseS[(w * 8 + c) * E + e] + rReg[c];
      row_token[p] = q >> 1;
      row_gate[p]  = topk_gate[q];
      pos[q]       = p;
    }
  }
}

// GEMM1: h = gather(x) @ W1[e]^T; fused SwiGLU -> a_buf (bf16).
// 256 thr / 2x2 waves; tile 128 tokens x 64 a-cols (128 h-cols). BK=64.
// Bs row grouping: [h1 c0..31 | h2 c0..31 | h1 c32..63 | h2 c32..63]; acc[i][j] pairs acc[i][j+2].
__global__ __launch_bounds__(256, 4)
void gemm1_kernel(const unsigned short* __restrict__ xb,
                  const unsigned short* __restrict__ W1b,
                  const float* __restrict__ b1,
                  const int* __restrict__ counts, const int* __restrict__ offsets,
                  const int* __restrict__ row_token,
                  unsigned short* __restrict__ a_buf) {
  const int e  = blockIdx.z;
  const int m0 = blockIdx.y * 128;
  const int n0 = blockIdx.x * 64;
  const int cnt = counts[e];
  if (m0 >= cnt) return;
  const int pairBase = offsets[e];

  __shared__ __align__(16) unsigned short As[128 * 64];   // unpadded (global_load_lds), XOR-swizzled
  __shared__ __align__(16) unsigned short Bs[128 * 64];
  __shared__ int tokS[128];

  const int tid = threadIdx.x;
  if (tid < 128) {
    int r = m0 + tid;
    tokS[tid] = (r < cnt) ? row_token[pairBase + r] : row_token[pairBase];  // clamp: safe garbage
  }
  __syncthreads();

  const int lane = tid & 63;
  const int wave = tid >> 6;
  const int quad = lane >> 4;
  const int l16  = lane & 15;
  const int lr   = lane >> 3;
  const int lc   = lane & 7;
  const int sw   = lc ^ (lr & 7);      // swizzled global chunk this lane fetches
  const int wr   = wave >> 1;
  const int wc   = wave & 1;

  const unsigned short* W1e = W1b + (size_t)e * TWO_F * D;
  const unsigned short* aptr[4];
  const unsigned short* bptr[4];
#pragma unroll
  for (int i = 0; i < 4; ++i) {
    int r = wave * 32 + i * 8 + lr;
    aptr[i] = xb + (size_t)tokS[r] * D + sw * 8;
    int g = r >> 5, s = r & 31;
    int wrow = (g & 1) * F + n0 + (g >> 1) * 32 + s;
    bptr[i] = W1e + (size_t)wrow * D + sw * 8;
  }
  unsigned short* AsW = As + (wave * 32) * 64;
  unsigned short* BsW = Bs + (wave * 32) * 64;

  f32x4 acc[4][4];
#pragma unroll
  for (int i = 0; i < 4; ++i)
#pragma unroll
    for (int j = 0; j < 4; ++j) acc[i][j] = (f32x4){0.f, 0.f, 0.f, 0.f};

  for (int k0 = 0; k0 < D; k0 += 64) {
#pragma unroll
    for (int i = 0; i < 4; ++i) load_lds16(aptr[i] + k0, AsW + i * 8 * 64);
#pragma unroll
    for (int i = 0; i < 4; ++i) load_lds16(bptr[i] + k0, BsW + i * 8 * 64);
    __syncthreads();
#pragma unroll
    for (int kk = 0; kk < 64; kk += 32) {
      bf16x8 af[4], bf[4];
#pragma unroll
      for (int i = 0; i < 4; ++i)
        af[i] = *frag_addr(As, wr * 64 + i * 16 + l16, kk, quad);
#pragma unroll
      for (int j = 0; j < 4; ++j)
        bf[j] = *frag_addr(Bs, wc * 64 + j * 16 + l16, kk, quad);
#pragma unroll
      for (int i = 0; i < 4; ++i)
#pragma unroll
        for (int j = 0; j < 4; ++j)
          acc[i][j] = __builtin_amdgcn_mfma_f32_16x16x32_bf16(af[i], bf[j], acc[i][j], 0, 0, 0);
    }
    __syncthreads();
  }

  // Epilogue: a = h1 * silu(h2); acc[i][j] (j=0,1 -> h1) pairs acc[i][j+2] (h2).
#pragma unroll
  for (int i = 0; i < 4; ++i) {
    int rb = wr * 64 + i * 16 + quad * 4;
#pragma unroll
    for (int j = 0; j < 2; ++j) {
      int col = n0 + wc * 32 + j * 16 + l16;
      float bh1 = b1[e * TWO_F + col];
      float bh2 = b1[e * TWO_F + F + col];
#pragma unroll
      for (int rg = 0; rg < 4; ++rg) {
        int r = rb + rg;
        if (m0 + r < cnt) {
          float h1 = acc[i][j][rg] + bh1;
          float h2 = acc[i][j + 2][rg] + bh2;
          float a  = h1 * (h2 / (1.f + __expf(-h2)));
          a_buf[(size_t)(pairBase + m0 + r) * F + col] = f32_to_bf16(a);
        }
      }
    }
  }
}

// GEMM2: y = a @ W2[e]^T + b2 -> y_buf (bf16, per-pair rows). NO atomics, no token scatter.
__global__ __launch_bounds__(256, 4)
void gemm2_kernel(const unsigned short* __restrict__ a_buf,
                  const unsigned short* __restrict__ W2b,
                  const float* __restrict__ b2,
                  const int* __restrict__ counts, const int* __restrict__ offsets,
                  unsigned short* __restrict__ y_buf, int totalPairs) {
  const int e  = blockIdx.z;
  const int m0 = blockIdx.y * 128;
  const int n0 = blockIdx.x * 128;
  const int cnt = counts[e];
  if (m0 >= cnt) return;
  const int pairBase = offsets[e];

  __shared__ __align__(16) unsigned short As[128 * 64];
  __shared__ __align__(16) unsigned short Bs[128 * 64];

  const int tid  = threadIdx.x;
  const int lane = tid & 63;
  const int wave = tid >> 6;
  const int quad = lane >> 4;
  const int l16  = lane & 15;
  const int lr   = lane >> 3;
  const int lc   = lane & 7;
  const int sw   = lc ^ (lr & 7);
  const int wr   = wave >> 1;
  const int wc   = wave & 1;

  const unsigned short* W2e = W2b + (size_t)e * D * F;
  const unsigned short* aptr[4];
  const unsigned short* bptr[4];
#pragma unroll
  for (int i = 0; i < 4; ++i) {
    int r = wave * 32 + i * 8 + lr;
    int g = pairBase + m0 + r;
    if (g > totalPairs - 1) g = totalPairs - 1;   // clamp: stay inside a_buf
    aptr[i] = a_buf + (size_t)g * F + sw * 8;
    bptr[i] = W2e + (size_t)(n0 + r) * F + sw * 8;
  }
  unsigned short* AsW = As + (wave * 32) * 64;
  unsigned short* BsW = Bs + (wave * 32) * 64;

  f32x4 acc[4][4];
#pragma unroll
  for (int i = 0; i < 4; ++i)
#pragma unroll
    for (int j = 0; j < 4; ++j) acc[i][j] = (f32x4){0.f, 0.f, 0.f, 0.f};

  for (int k0 = 0; k0 < F; k0 += 64) {
#pragma unroll
    for (int i = 0; i < 4; ++i) load_lds16(aptr[i] + k0, AsW + i * 8 * 64);
#pragma unroll
    for (int i = 0; i < 4; ++i) load_lds16(bptr[i] + k0, BsW + i * 8 * 64);
    __syncthreads();
#pragma unroll
    for (int kk = 0; kk < 64; kk += 32) {
      bf16x8 af[4], bf[4];
#pragma unroll
      for (int i = 0; i < 4; ++i)
        af[i] = *frag_addr(As, wr * 64 + i * 16 + l16, kk, quad);
#pragma unroll
      for (int j = 0; j < 4; ++j)
        bf[j] = *frag_addr(Bs, wc * 64 + j * 16 + l16, kk, quad);
#pragma unroll
      for (int i = 0; i < 4; ++i)
#pragma unroll
        for (int j = 0; j < 4; ++j)
          acc[i][j] = __builtin_amdgcn_mfma_f32_16x16x32_bf16(af[i], bf[j], acc[i][j], 0, 0, 0);
    }
    __syncthreads();
  }

#pragma unroll
  for (int j = 0; j < 4; ++j) {
    int col = n0 + wc * 64 + j * 16 + l16;
    float b2v = b2[e * D + col];
#pragma unroll
    for (int i = 0; i < 4; ++i) {
      int rb = wr * 64 + i * 16 + quad * 4;
#pragma unroll
      for (int rg = 0; rg < 4; ++rg) {
        int r = rb + rg;
        if (m0 + r < cnt)
          y_buf[(size_t)(pairBase + m0 + r) * D + col] = f32_to_bf16(acc[i][j][rg] + b2v);
      }
    }
  }
}

// Combine: out[t] = g0 * y[pos[2t]] + g1 * y[pos[2t+1]]  (streaming, overwrites out fully)
__global__ void combine_kernel(const unsigned short* __restrict__ y_buf,
                               const int* __restrict__ pos,
                               const float* __restrict__ topk_gate,
                               float* __restrict__ out) {
  const int t = blockIdx.x;
  const int d = threadIdx.x * 4;
  const int p0 = pos[2 * t], p1 = pos[2 * t + 1];
  const float g0 = topk_gate[2 * t], g1 = topk_gate[2 * t + 1];
  ushort4 a = *(const ushort4*)(y_buf + (size_t)p0 * D + d);
  ushort4 b = *(const ushort4*)(y_buf + (size_t)p1 * D + d);
  float4 o;
  o.x = g0 * bf16_to_f32(a.x) + g1 * bf16_to_f32(b.x);
  o.y = g0 * bf16_to_f32(a.y) + g1 * bf16_to_f32(b.y);
  o.z = g0 * bf16_to_f32(a.z) + g1 * bf16_to_f32(b.z);
  o.w = g0 * bf16_to_f32(a.w) + g1 * bf16_to_f32(b.w);
  *(float4*)(out + (size_t)t * D + d) = o;
}

}  // namespace

extern "C" void kernel_launch(void* const* d_in, const int* in_sizes, int n_in,
                              void* d_out, int out_size, void* d_ws, size_t ws_size,
                              hipStream_t stream) {
  (void)n_in; (void)out_size; (void)ws_size;
  const float* x    = (const float*)d_in[0];
  const float* Wr   = (const float*)d_in[1];
  const float* temp = (const float*)d_in[2];
  const float* W1   = (const float*)d_in[3];
  const float* b1   = (const float*)d_in[4];
  const float* W2   = (const float*)d_in[5];
  const float* b2   = (const float*)d_in[6];
  float* out = (float*)d_out;
  const int T = in_sizes[0] / D;   // 4096

  // workspace layout (~137 MB). y_buf ALIASES W1b: W1b is dead after gemm1, and same-stream
  // ordering guarantees gemm1 completes before gemm2 writes y_buf.
  char* ws = (char*)d_ws;
  size_t off = 0;
  unsigned short* xb    = (unsigned short*)(ws + off); off += (size_t)T * D * 2;
  unsigned short* W1b   = (unsigned short*)(ws + off); off += (size_t)E * TWO_F * D * 2;
  unsigned short* W2b   = (unsigned short*)(ws + off); off += (size_t)E * D * F * 2;
  unsigned short* a_buf = (unsigned short*)(ws + off); off += (size_t)T * 2 * F * 2;
  int*   counts    = (int*)(ws + off); off += 64;
  int*   offsets   = (int*)(ws + off); off += 64;
  int*   topk_idx  = (int*)(ws + off); off += (size_t)T * 2 * 4;
  float* topk_gate = (float*)(ws + off); off += (size_t)T * 2 * 4;
  int*   row_token = (int*)(ws + off); off += (size_t)T * 2 * 4;
  float* row_gate  = (float*)(ws + off); off += (size_t)T * 2 * 4;
  int*   pos       = (int*)(ws + off); off += (size_t)T * 2 * 4;
  unsigned short* y_buf = W1b;   // alias (16 MB needed, 64 MB available)

  const long long nx = (long long)T * D;
  const long long n1 = (long long)E * TWO_F * D;
  const long long n2 = (long long)E * D * F;

  router_kernel<<<(T + 3) / 4, 256, 0, stream>>>(x, Wr, temp, topk_idx, topk_gate, T);
  assign_kernel<<<1, 1024, 0, stream>>>(topk_idx, topk_gate, counts, offsets,
                                        row_token, row_gate, pos, T);
  cvt_all_kernel<<<(int)((nx + n1 + n2) / 2048), 256, 0, stream>>>(x, W1, W2, xb, W1b, W2b,
                                                                   nx, n1);
  gemm1_kernel<<<dim3(F / 64, (T * 2 + 127) / 128, E), 256, 0, stream>>>(xb, W1b, b1, counts,
                                                                         offsets, row_token, a_buf);
  gemm2_kernel<<<dim3(D / 128, (T * 2 + 127) / 128, E), 256, 0, stream>>>(a_buf, W2b, b2, counts,
                                                                          offsets, y_buf, T * 2);
  combine_kernel<<<T, 256, 0, stream>>>(y_buf, pos, topk_gate, out);
}